// Round 1
// baseline (1270.086 us; speedup 1.0000x reference)
//
#include <hip/hip_runtime.h>
#include <math.h>

// ---------------- constants ----------------
#define NN 512
#define CSD 384
#define CZD 128
#define HD 8
#define CD 128
#define PQD 8
#define PVD 8
#define EPSV 1e-8f
#define INFV 100000.0f

// ws float offsets
#define OFF_QN    ((size_t)0)                     // 512*4
#define OFF_TR    (OFF_QN + 512*4)                // 512*3
#define OFF_Q     (OFF_TR + 512*3)                // 512*1024
#define OFF_KV    (OFF_Q + 512*1024)              // 512*2048
#define OFF_QPR   (OFF_KV + (size_t)512*2048)     // 512*192
#define OFF_KPR   (OFF_QPR + 512*192)
#define OFF_QPTS  (OFF_KPR + 512*192)             // 512*192
#define OFF_KPTS  (OFF_QPTS + 512*192)
#define OFF_QSQ   (OFF_KPTS + 512*192)            // 512*8
#define OFF_KSQ   (OFF_QSQ + 512*8)
#define OFF_VGR   (OFF_KSQ + 512*8)               // 512*128
#define OFF_VGG   (OFF_VGR + 512*128)             // 512*1024
#define OFF_ZB    (OFF_VGG + (size_t)512*1024)    // 512*512*8
#define OFF_A     (OFF_ZB + (size_t)512*512*8)    // 8*512*512
#define OFF_AZ    (OFF_A + (size_t)8*512*512)     // 512*1024
#define OFF_O     (OFF_AZ + (size_t)512*1024)     // 512*1024
#define OFF_OG    (OFF_O + (size_t)512*1024)      // 512*1024
#define OFF_SB    (OFF_OG + (size_t)512*1024)     // 512*64
#define OFF_FEATS (OFF_SB + 512*64)               // 512*2496

__device__ __forceinline__ void qrot(const float q[4], const float* v, float* out) {
    float qw = q[0], qx = q[1], qy = q[2], qz = q[3];
    float ux = qy*v[2] - qz*v[1];
    float uy = qz*v[0] - qx*v[2];
    float uz = qx*v[1] - qy*v[0];
    float uux = qy*uz - qz*uy;
    float uuy = qz*ux - qx*uz;
    float uuz = qx*uy - qy*ux;
    out[0] = v[0] + 2.0f*(qw*ux + uux);
    out[1] = v[1] + 2.0f*(qw*uy + uuy);
    out[2] = v[2] + 2.0f*(qw*uz + uuz);
}

// ---------------- kernels ----------------

__global__ void k_prep(const float* __restrict__ T, float* __restrict__ qn, float* __restrict__ tr) {
    int n = blockIdx.x*blockDim.x + threadIdx.x;
    if (n >= NN) return;
    float q0=T[n*16+0], q1=T[n*16+1], q2=T[n*16+2], q3=T[n*16+3];
    float inv = 1.0f/sqrtf(q0*q0+q1*q1+q2*q2+q3*q3 + EPSV);
    qn[n*4+0]=q0*inv; qn[n*4+1]=q1*inv; qn[n*4+2]=q2*inv; qn[n*4+3]=q3*inv;
    tr[n*3+0]=T[n*16+4]; tr[n*3+1]=T[n*16+5]; tr[n*3+2]=T[n*16+6];
}

__global__ void k_gemm_bias(const float* __restrict__ X, const float* __restrict__ W,
                            const float* __restrict__ b, float* __restrict__ out, int M) {
    int n = blockIdx.x;
    int m = blockIdx.y*blockDim.x + threadIdx.x;
    if (m >= M) return;
    const float* x = X + (size_t)n*CSD;
    float acc = b[m];
    #pragma unroll 4
    for (int k=0;k<CSD;k++) acc += x[k]*W[(size_t)k*M+m];
    out[(size_t)n*M+m] = acc;
}

__global__ void k_points(const float* __restrict__ raw, const float* __restrict__ qn,
                         const float* __restrict__ tr, float* __restrict__ pts,
                         float* __restrict__ sq) {
    int n = blockIdx.x; int m = threadIdx.x; // 64 threads
    float p[3] = {raw[n*192 + m], raw[n*192 + 64 + m], raw[n*192 + 128 + m]};
    float q[4] = {qn[n*4],qn[n*4+1],qn[n*4+2],qn[n*4+3]};
    float r[3]; qrot(q,p,r);
    r[0]+=tr[n*3]; r[1]+=tr[n*3+1]; r[2]+=tr[n*3+2];
    pts[n*192+m*3+0]=r[0]; pts[n*192+m*3+1]=r[1]; pts[n*192+m*3+2]=r[2];
    float s = r[0]*r[0]+r[1]*r[1]+r[2]*r[2];
    s += __shfl_down(s,4,8);
    s += __shfl_down(s,2,8);
    s += __shfl_down(s,1,8);
    if ((m&7)==0) sq[n*8 + (m>>3)] = s;
}

__global__ void k_vg(const float* __restrict__ vgr, const float* __restrict__ g,
                     const float* __restrict__ W_mg, const float* __restrict__ qn,
                     const float* __restrict__ tr, float* __restrict__ vgg) {
    int n = blockIdx.x; int o = threadIdx.x; // 64 threads
    float in[16];
    #pragma unroll
    for (int c=0;c<16;c++){
        float acc=0.0f;
        #pragma unroll
        for (int i=0;i<8;i++)  acc += W_mg[o*16+i]*vgr[n*128+i*16+c];
        #pragma unroll
        for (int i=8;i<16;i++) acc += W_mg[o*16+i]*g[n*128+(i-8)*16+c];
        in[c]=acc;
    }
    float q[4]={qn[n*4],qn[n*4+1],qn[n*4+2],qn[n*4+3]};
    float t0=tr[n*3], t1=tr[n*3+1], t2=tr[n*3+2];
    float out[16];
    out[0]=in[0];
    qrot(q,in+1,out+1);
    qrot(q,in+4,out+4);
    float w=in[10];
    qrot(q,in+7,out+7);
    out[7]+=w*t0; out[8]+=w*t1; out[9]+=w*t2;
    #pragma unroll
    for (int c=10;c<16;c++) out[c]=in[c];
    #pragma unroll
    for (int c=0;c<16;c++) vgg[(size_t)n*1024+o*16+c]=out[c];
}

__global__ void k_zb(const float* __restrict__ z, const float* __restrict__ W_b,
                     float* __restrict__ zb) {
    int idx = blockIdx.x*blockDim.x + threadIdx.x; // 2097152
    int h = idx & 7;
    int ij = idx >> 3;
    const float* zr = z + (size_t)ij*CZD;
    float acc=0.0f;
    #pragma unroll 4
    for (int c=0;c<CZD;c++) acc += zr[c]*W_b[c*HD+h];
    zb[idx]=acc;
}

__global__ void k_score(const float* __restrict__ kv, const float* __restrict__ q,
                        const float* __restrict__ qpts, const float* __restrict__ kpts,
                        const float* __restrict__ Qsq, const float* __restrict__ Ksq,
                        const float* __restrict__ zb, const float* __restrict__ b_b,
                        const float* __restrict__ hwraw, const float* __restrict__ sw,
                        const float* __restrict__ mask, float* __restrict__ a) {
    int i = blockIdx.x, h = blockIdx.y, j = threadIdx.x; // block 512
    __shared__ float qs[CD];
    __shared__ float qps[24];
    __shared__ float red[NN];
    if (j < CD) qs[j] = q[(size_t)i*1024 + h*CD + j];
    if (j < 24) qps[j] = qpts[i*192 + h*24 + j];
    __syncthreads();
    const float* kr = kv + (size_t)j*2048 + h*256;
    float qk=0.0f;
    #pragma unroll 8
    for (int c=0;c<CD;c++) qk += qs[c]*kr[c];
    const float* kp = kpts + j*192 + h*24;
    float dot=0.0f;
    #pragma unroll
    for (int d=0;d<24;d++) dot += qps[d]*kp[d];
    float hw = logf(1.0f+expf(hwraw[h])) * 0.09622504486493763f; // sqrt(1/108)
    float pt = Qsq[i*8+h] + Ksq[j*8+h] - 2.0f*dot;
    float score = 0.05103103630798287f*qk                     // sqrt(1/384)
                + 0.5773502691896258f*(zb[((size_t)(i*NN+j))*8 + h] + b_b[h])  // sqrt(1/3)
                - 0.5f*hw*pt
                + INFV*(mask[i]*mask[j]-1.0f);
    score *= sw[h];
    red[j]=score; __syncthreads();
    for (int st=NN/2; st>0; st>>=1){ if (j<st) red[j]=fmaxf(red[j],red[j+st]); __syncthreads(); }
    float mx = red[0]; __syncthreads();
    float e = expf(score-mx);
    red[j]=e; __syncthreads();
    for (int st=NN/2; st>0; st>>=1){ if (j<st) red[j]+=red[j+st]; __syncthreads(); }
    float inv = 1.0f/red[0];
    a[((size_t)h*NN+i)*NN + j] = e*inv;
}

__global__ void k_apply_o(const float* __restrict__ a, const float* __restrict__ kv,
                          float* __restrict__ obuf) {
    int i=blockIdx.x, h=blockIdx.y, c=threadIdx.x; // 128
    __shared__ float ar[NN];
    for (int t=c;t<NN;t+=128) ar[t]=a[((size_t)h*NN+i)*NN+t];
    __syncthreads();
    float acc=0.0f;
    for (int j=0;j<NN;j++) acc += ar[j]*kv[(size_t)j*2048 + h*256 + 128 + c];
    obuf[(size_t)i*1024 + h*128 + c]=acc;
}

__global__ void k_apply_og(const float* __restrict__ a, const float* __restrict__ vgg,
                           float* __restrict__ og) {
    int i=blockIdx.x, h=blockIdx.y, t=threadIdx.x; // 128 (p*16+c)
    __shared__ float ar[NN];
    for (int x=t;x<NN;x+=128) ar[x]=a[((size_t)h*NN+i)*NN+x];
    __syncthreads();
    float acc=0.0f;
    for (int j=0;j<NN;j++) acc += ar[j]*vgg[(size_t)j*1024 + h*128 + t];
    og[(size_t)i*1024 + h*128 + t]=acc;
}

__global__ void k_az(const float* __restrict__ a, const float* __restrict__ z,
                     float* __restrict__ az) {
    int i=blockIdx.x, zc=threadIdx.x; // 128
    float acc[8]={0,0,0,0,0,0,0,0};
    for (int j=0;j<NN;j++){
        float zv = z[((size_t)(i*NN)+j)*CZD + zc];
        #pragma unroll
        for (int h=0;h<8;h++) acc[h] += a[((size_t)h*NN+i)*NN+j]*zv;
    }
    #pragma unroll
    for (int h=0;h<8;h++) az[(size_t)i*1024 + h*128 + zc]=acc[h];
}

__global__ void k_S(const float* __restrict__ a, const float* __restrict__ qn,
                    const float* __restrict__ tr, float* __restrict__ S) {
    int i=blockIdx.x; int t=threadIdx.x; // 64
    int h=t>>3, cmp=t&7;
    float acc=0.0f;
    for (int j=0;j<NN;j++){
        float x = cmp<4 ? qn[j*4+cmp] : (cmp<7 ? tr[j*3+cmp-4] : 1.0f);
        acc += a[((size_t)h*NN+i)*NN+j]*x;
    }
    S[i*64+t]=acc;
}

__global__ void k_finalize(const float* __restrict__ obuf, const float* __restrict__ az,
                           const float* __restrict__ W_dz, const float* __restrict__ b_dz,
                           float* __restrict__ og, const float* __restrict__ S,
                           const float* __restrict__ qn, const float* __restrict__ tr,
                           float* __restrict__ feats) {
    int i=blockIdx.x, h=blockIdx.y, t=threadIdx.x; // 128
    float* f = feats + (size_t)i*2496 + h*312;
    // o (128)
    f[32+t] = obuf[(size_t)i*1024+h*128+t];
    if (t < 32) {
        // o_pair = az @ W_dz + b_dz
        float acc = b_dz[t];
        const float* azr = az + (size_t)i*1024 + h*128;
        #pragma unroll 4
        for (int zc=0;zc<128;zc++) acc += azr[zc]*W_dz[zc*32+t];
        f[t]=acc;
    } else if (t >= 64 && t < 72) {
        int p = t-64;
        float* ogp = og + (size_t)i*1024 + h*128 + p*16;
        float in[16];
        #pragma unroll
        for (int c=0;c<16;c++) in[c]=ogp[c];
        float qc[4]={qn[i*4], -qn[i*4+1], -qn[i*4+2], -qn[i*4+3]};
        float t0=tr[i*3], t1=tr[i*3+1], t2=tr[i*3+2];
        float out[16];
        out[0]=in[0];
        qrot(qc,in+1,out+1);
        qrot(qc,in+4,out+4);
        float w=in[10];
        float tmp[3]={in[7]-w*t0, in[8]-w*t1, in[9]-w*t2};
        qrot(qc,tmp,out+7);
        #pragma unroll
        for (int c2=10;c2<16;c2++) out[c2]=in[c2];
        float n1=EPSV, n2=EPSV;
        #pragma unroll
        for (int c2=0;c2<10;c2++) n1 += out[c2]*out[c2];
        #pragma unroll
        for (int c2=10;c2<16;c2++) n2 += out[c2]*out[c2];
        n1=sqrtf(n1); n2=sqrtf(n2);
        #pragma unroll
        for (int c2=0;c2<16;c2++){ f[168+p*16+c2]=out[c2]; ogp[c2]=out[c2]; }
        f[296+p*2]=n1; f[296+p*2+1]=n2;
    } else if (t == 96) {
        // o_rel via linearity: quat_mul(qc_i, S4), qrot(qc_i, S3 - A*tr_i)
        float qc0=qn[i*4], qc1=-qn[i*4+1], qc2=-qn[i*4+2], qc3=-qn[i*4+3];
        const float* Sr = S + i*64 + h*8;
        float b0=Sr[0], b1=Sr[1], b2=Sr[2], b3=Sr[3];
        f[160] = qc0*b0 - qc1*b1 - qc2*b2 - qc3*b3;
        f[161] = qc0*b1 + qc1*b0 + qc2*b3 - qc3*b2;
        f[162] = qc0*b2 - qc1*b3 + qc2*b0 + qc3*b1;
        f[163] = qc0*b3 + qc1*b2 - qc2*b1 + qc3*b0;
        float A = Sr[7];
        float v[3]={Sr[4]-A*tr[i*3], Sr[5]-A*tr[i*3+1], Sr[6]-A*tr[i*3+2]};
        float qc[4]={qc0,qc1,qc2,qc3};
        float r[3]; qrot(qc,v,r);
        f[164]=r[0]; f[165]=r[1]; f[166]=r[2]; f[167]=0.0f;
    }
}

__global__ void k_gout(const float* __restrict__ og, const float* __restrict__ W_geo,
                       float* __restrict__ gout) {
    int idx = blockIdx.x*blockDim.x+threadIdx.x; // 65536
    int c = idx & 15;
    int o = (idx>>4) & 7;
    int n = idx >> 7;
    float acc=0.0f;
    #pragma unroll 4
    for (int i2=0;i2<64;i2++) acc += W_geo[o*64+i2]*og[(size_t)n*1024 + i2*16 + c];
    gout[(size_t)n*128 + o*16 + c]=acc;
}

__global__ void k_sout(const float* __restrict__ feats, const float* __restrict__ W_out,
                       const float* __restrict__ b_out, float* __restrict__ sout) {
    int n=blockIdx.x; int m=blockIdx.y*blockDim.x+threadIdx.x;
    if (m>=CSD) return;
    const float* fr = feats + (size_t)n*2496;
    float acc=b_out[m];
    #pragma unroll 4
    for (int k=0;k<2496;k++) acc += fr[k]*W_out[(size_t)k*CSD+m];
    sout[(size_t)n*CSD+m]=acc;
}

// ---------------- launch ----------------

extern "C" void kernel_launch(void* const* d_in, const int* in_sizes, int n_in,
                              void* d_out, int out_size, void* d_ws, size_t ws_size,
                              hipStream_t stream) {
    const float* s     = (const float*)d_in[0];
    const float* g     = (const float*)d_in[1];
    const float* z     = (const float*)d_in[2];
    const float* T     = (const float*)d_in[3];
    const float* mask  = (const float*)d_in[4];
    const float* W_q   = (const float*)d_in[5];
    const float* b_q   = (const float*)d_in[6];
    const float* W_kv  = (const float*)d_in[7];
    const float* b_kv  = (const float*)d_in[8];
    const float* W_qp  = (const float*)d_in[9];
    const float* b_qp  = (const float*)d_in[10];
    const float* W_kp  = (const float*)d_in[11];
    const float* b_kp  = (const float*)d_in[12];
    const float* W_vg  = (const float*)d_in[13];
    const float* b_vg  = (const float*)d_in[14];
    const float* W_mg  = (const float*)d_in[15];
    const float* W_b   = (const float*)d_in[16];
    const float* b_b   = (const float*)d_in[17];
    const float* W_dz  = (const float*)d_in[18];
    const float* b_dz  = (const float*)d_in[19];
    const float* hw    = (const float*)d_in[20];
    const float* sw    = (const float*)d_in[21];
    const float* W_out = (const float*)d_in[22];
    const float* b_out = (const float*)d_in[23];
    const float* W_geo = (const float*)d_in[24];

    float* ws   = (float*)d_ws;
    float* out  = (float*)d_out;

    float* qn   = ws + OFF_QN;
    float* tr   = ws + OFF_TR;
    float* qbuf = ws + OFF_Q;
    float* kv   = ws + OFF_KV;
    float* qpr  = ws + OFF_QPR;
    float* kpr  = ws + OFF_KPR;
    float* qpts = ws + OFF_QPTS;
    float* kpts = ws + OFF_KPTS;
    float* Qsq  = ws + OFF_QSQ;
    float* Ksq  = ws + OFF_KSQ;
    float* vgr  = ws + OFF_VGR;
    float* vgg  = ws + OFF_VGG;
    float* zb   = ws + OFF_ZB;
    float* a    = ws + OFF_A;
    float* az   = ws + OFF_AZ;
    float* obuf = ws + OFF_O;
    float* og   = ws + OFF_OG;
    float* Sbuf = ws + OFF_SB;
    float* feats= ws + OFF_FEATS;

    k_prep<<<2,256,0,stream>>>(T,qn,tr);
    k_gemm_bias<<<dim3(NN,4),256,0,stream>>>(s,W_q,b_q,qbuf,1024);
    k_gemm_bias<<<dim3(NN,8),256,0,stream>>>(s,W_kv,b_kv,kv,2048);
    k_gemm_bias<<<dim3(NN,1),256,0,stream>>>(s,W_qp,b_qp,qpr,192);
    k_gemm_bias<<<dim3(NN,1),256,0,stream>>>(s,W_kp,b_kp,kpr,192);
    k_gemm_bias<<<dim3(NN,1),256,0,stream>>>(s,W_vg,b_vg,vgr,128);
    k_points<<<NN,64,0,stream>>>(qpr,qn,tr,qpts,Qsq);
    k_points<<<NN,64,0,stream>>>(kpr,qn,tr,kpts,Ksq);
    k_vg<<<NN,64,0,stream>>>(vgr,g,W_mg,qn,tr,vgg);
    k_zb<<<8192,256,0,stream>>>(z,W_b,zb);
    k_score<<<dim3(NN,HD),NN,0,stream>>>(kv,qbuf,qpts,kpts,Qsq,Ksq,zb,b_b,hw,sw,mask,a);
    k_apply_o<<<dim3(NN,HD),128,0,stream>>>(a,kv,obuf);
    k_apply_og<<<dim3(NN,HD),128,0,stream>>>(a,vgg,og);
    k_az<<<NN,128,0,stream>>>(a,z,az);
    k_S<<<NN,64,0,stream>>>(a,qn,tr,Sbuf);
    k_finalize<<<dim3(NN,HD),128,0,stream>>>(obuf,az,W_dz,b_dz,og,Sbuf,qn,tr,feats);
    k_gout<<<256,256,0,stream>>>(og,W_geo,out + (size_t)NN*CSD);
    k_sout<<<dim3(NN,3),128,0,stream>>>(feats,W_out,b_out,out);
}

// Round 2
// 554.827 us; speedup vs baseline: 2.2892x; 2.2892x over previous
//
#include <hip/hip_runtime.h>
#include <math.h>

// ---------------- constants ----------------
#define NN 512
#define CSD 384
#define CZD 128
#define HD 8
#define CD 128
#define EPSV 1e-8f
#define INFV 100000.0f

// ---------------- ws float offsets ----------------
#define OFF_QN    ((size_t)0)
#define OFF_TR    ((size_t)2048)
#define OFF_QSQ   ((size_t)3584)
#define OFF_KSQ   ((size_t)7680)
#define OFF_ROWT  ((size_t)11776)
#define OFF_COLT  ((size_t)15872)
#define OFF_SB    ((size_t)19968)
#define OFF_QBUF  ((size_t)52736)
#define OFF_KV    ((size_t)577024)
#define OFF_QPTS  ((size_t)1625600)
#define OFF_KPTS  ((size_t)1723904)
#define OFF_VGG   ((size_t)1822208)
#define OFF_ZB    ((size_t)2346496)
#define OFF_A     ((size_t)4443648)
#define OFF_X     ((size_t)6540800)
// union region (lifetimes disjoint, stream-ordered):
#define OFF_QPR   (OFF_X)                    // dead after k_points
#define OFF_KPR   (OFF_X + 98304)            // dead after k_points
#define OFF_VGR   (OFF_X + 196608)           // dead after k_vg
#define OFF_U     (OFF_X)                    // written k_uv, dead after scorefill
#define OFF_V     (OFF_X + 655360)           // "
#define OFF_AZ    (OFF_X)                    // written k_az (after scorefill)
#define OFF_O     (OFF_X + 524288)
#define OFF_OG    (OFF_X + 1048576)
#define OFF_FEATS (OFF_X + 1572864)

__device__ __forceinline__ void qrot(const float q[4], const float* v, float* out) {
    float qw = q[0], qx = q[1], qy = q[2], qz = q[3];
    float ux = qy*v[2] - qz*v[1];
    float uy = qz*v[0] - qx*v[2];
    float uz = qx*v[1] - qy*v[0];
    float uux = qy*uz - qz*uy;
    float uuy = qz*ux - qx*uz;
    float uuz = qx*uy - qy*ux;
    out[0] = v[0] + 2.0f*(qw*ux + uux);
    out[1] = v[1] + 2.0f*(qw*uy + uuy);
    out[2] = v[2] + 2.0f*(qw*uz + uuz);
}

// ---------- shared tiled-GEMM core: 64x64 tile, BK=32, 256 thr, 4x4/thread ----------
__device__ __forceinline__ void gemm_tiles(const float* __restrict__ A, int lda,
                                           const float* __restrict__ B, int ldb,
                                           int m0, int n0, int k0, int nk,
                                           float acc[4][4], float* AsT, float* Bs) {
    int t = threadIdx.x;
    int tx = t & 15, ty = t >> 4;
    for (int kc = 0; kc < nk; kc++) {
        int kb = k0 + kc*32;
        #pragma unroll
        for (int l = 0; l < 2; l++) {
            int f = t + l*256;                       // 0..511: 64 rows x 8 f4
            int row = f >> 3, k4 = (f & 7) << 2;
            float4 v = *(const float4*)(A + (size_t)(m0+row)*lda + kb + k4);
            AsT[(k4+0)*68 + row] = v.x;
            AsT[(k4+1)*68 + row] = v.y;
            AsT[(k4+2)*68 + row] = v.z;
            AsT[(k4+3)*68 + row] = v.w;
        }
        #pragma unroll
        for (int l = 0; l < 2; l++) {
            int f = t + l*256;                       // 32 rows x 16 f4
            int row = f >> 4, c4 = (f & 15) << 2;
            *(float4*)(Bs + row*64 + c4) = *(const float4*)(B + (size_t)(kb+row)*ldb + n0 + c4);
        }
        __syncthreads();
        #pragma unroll
        for (int kk = 0; kk < 32; kk++) {
            float4 av = *(const float4*)(AsT + kk*68 + ty*4);
            float4 bv = *(const float4*)(Bs + kk*64 + tx*4);
            acc[0][0] += av.x*bv.x; acc[0][1] += av.x*bv.y; acc[0][2] += av.x*bv.z; acc[0][3] += av.x*bv.w;
            acc[1][0] += av.y*bv.x; acc[1][1] += av.y*bv.y; acc[1][2] += av.y*bv.z; acc[1][3] += av.y*bv.w;
            acc[2][0] += av.z*bv.x; acc[2][1] += av.z*bv.y; acc[2][2] += av.z*bv.z; acc[2][3] += av.z*bv.w;
            acc[3][0] += av.w*bv.x; acc[3][1] += av.w*bv.y; acc[3][2] += av.w*bv.z; acc[3][3] += av.w*bv.w;
        }
        __syncthreads();
    }
}

// ---------------- kernels ----------------

__global__ void k_prep(const float* __restrict__ T, float* __restrict__ qn, float* __restrict__ tr) {
    int n = blockIdx.x*blockDim.x + threadIdx.x;
    if (n >= NN) return;
    float q0=T[n*16+0], q1=T[n*16+1], q2=T[n*16+2], q3=T[n*16+3];
    float inv = 1.0f/sqrtf(q0*q0+q1*q1+q2*q2+q3*q3 + EPSV);
    qn[n*4+0]=q0*inv; qn[n*4+1]=q1*inv; qn[n*4+2]=q2*inv; qn[n*4+3]=q3*inv;
    tr[n*3+0]=T[n*16+4]; tr[n*3+1]=T[n*16+5]; tr[n*3+2]=T[n*16+6];
}

// all five projections in one launch; blockIdx.y segments the output space
__global__ __launch_bounds__(256) void k_proj_all(const float* __restrict__ s,
    const float* __restrict__ W_q,  const float* __restrict__ b_q,  float* __restrict__ qbuf,
    const float* __restrict__ W_kv, const float* __restrict__ b_kv, float* __restrict__ kvb,
    const float* __restrict__ W_qp, const float* __restrict__ b_qp, float* __restrict__ qpr,
    const float* __restrict__ W_kp, const float* __restrict__ b_kp, float* __restrict__ kpr,
    const float* __restrict__ W_vg, const float* __restrict__ b_vg, float* __restrict__ vgr) {
    __shared__ float AsT[32*68];
    __shared__ float Bs[32*64];
    int ny = blockIdx.y;
    const float* W; const float* bias; float* C; int N; int n0;
    if (ny < 16)      { W=W_q;  bias=b_q;  C=qbuf; N=1024; n0=ny*64; }
    else if (ny < 48) { W=W_kv; bias=b_kv; C=kvb;  N=2048; n0=(ny-16)*64; }
    else if (ny < 51) { W=W_qp; bias=b_qp; C=qpr;  N=192;  n0=(ny-48)*64; }
    else if (ny < 54) { W=W_kp; bias=b_kp; C=kpr;  N=192;  n0=(ny-51)*64; }
    else              { W=W_vg; bias=b_vg; C=vgr;  N=128;  n0=(ny-54)*64; }
    int m0 = blockIdx.x*64;
    float acc[4][4] = {};
    gemm_tiles(s, CSD, W, N, m0, n0, 0, 12, acc, AsT, Bs);
    int tx = threadIdx.x & 15, ty = threadIdx.x >> 4;
    float4 bb = *(const float4*)(bias + n0 + tx*4);
    #pragma unroll
    for (int rr = 0; rr < 4; rr++) {
        float4 o = make_float4(acc[rr][0]+bb.x, acc[rr][1]+bb.y, acc[rr][2]+bb.z, acc[rr][3]+bb.w);
        *(float4*)(C + (size_t)(m0+ty*4+rr)*N + n0 + tx*4) = o;
    }
}

__global__ __launch_bounds__(64) void k_points(const float* __restrict__ raw, const float* __restrict__ qn,
                         const float* __restrict__ tr, float* __restrict__ pts,
                         float* __restrict__ sq) {
    int n = blockIdx.x; int m = threadIdx.x; // 64
    float p[3] = {raw[n*192 + m], raw[n*192 + 64 + m], raw[n*192 + 128 + m]};
    float q[4] = {qn[n*4],qn[n*4+1],qn[n*4+2],qn[n*4+3]};
    float r[3]; qrot(q,p,r);
    r[0]+=tr[n*3]; r[1]+=tr[n*3+1]; r[2]+=tr[n*3+2];
    pts[n*192+m*3+0]=r[0]; pts[n*192+m*3+1]=r[1]; pts[n*192+m*3+2]=r[2];
    float s = r[0]*r[0]+r[1]*r[1]+r[2]*r[2];
    s += __shfl_down(s,4,8);
    s += __shfl_down(s,2,8);
    s += __shfl_down(s,1,8);
    if ((m&7)==0) sq[n*8 + (m>>3)] = s;
}

__global__ __launch_bounds__(64) void k_vg(const float* __restrict__ vgr, const float* __restrict__ g,
                     const float* __restrict__ W_mg, const float* __restrict__ qn,
                     const float* __restrict__ tr, float* __restrict__ vgg) {
    int n = blockIdx.x; int o = threadIdx.x; // 64
    float in[16];
    #pragma unroll
    for (int c=0;c<16;c++){
        float acc=0.0f;
        #pragma unroll
        for (int i=0;i<8;i++)  acc += W_mg[o*16+i]*vgr[n*128+i*16+c];
        #pragma unroll
        for (int i=8;i<16;i++) acc += W_mg[o*16+i]*g[n*128+(i-8)*16+c];
        in[c]=acc;
    }
    float q[4]={qn[n*4],qn[n*4+1],qn[n*4+2],qn[n*4+3]};
    float t0=tr[n*3], t1=tr[n*3+1], t2=tr[n*3+2];
    float out[16];
    out[0]=in[0];
    qrot(q,in+1,out+1);
    qrot(q,in+4,out+4);
    float w=in[10];
    qrot(q,in+7,out+7);
    out[7]+=w*t0; out[8]+=w*t1; out[9]+=w*t2;
    #pragma unroll
    for (int c=10;c<16;c++) out[c]=in[c];
    #pragma unroll
    for (int c=0;c<16;c++) vgg[(size_t)n*1024+o*16+c]=out[c];
}

// build fused score operands: U[h][i][160], V[h][160][j] (V pre-transposed), row/col terms
__global__ __launch_bounds__(256) void k_uv(const float* __restrict__ qbuf, const float* __restrict__ kvb,
                    const float* __restrict__ qpts, const float* __restrict__ kpts,
                    const float* __restrict__ Qsq, const float* __restrict__ Ksq,
                    const float* __restrict__ hwraw, const float* __restrict__ b_b,
                    float* __restrict__ U, float* __restrict__ V,
                    float* __restrict__ rowt, float* __restrict__ colt) {
    int i = blockIdx.x; int t = threadIdx.x;
    #pragma unroll
    for (int h = 0; h < 8; h++) {
        float hw = log1pf(expf(hwraw[h])) * 0.09622504486493763f; // softplus * sqrt(1/108)
        if (t < 160) {
            float u, v;
            if (t < 128) {
                u = 0.05103103630798287f * qbuf[(size_t)i*1024 + h*128 + t]; // sqrt(1/384)
                v = kvb[(size_t)i*2048 + h*256 + t];
            } else if (t < 152) {
                int d = t - 128;
                u = hw * qpts[i*192 + h*24 + d];
                v = kpts[i*192 + h*24 + d];
            } else { u = 0.0f; v = 0.0f; }
            U[((size_t)h*512 + i)*160 + t] = u;
            V[((size_t)h*160 + t)*512 + i] = v;
        }
        if (t == 160) rowt[h*512+i] = -0.5f*hw*Qsq[i*8+h] + 0.5773502691896258f*b_b[h] - INFV;
        if (t == 161) colt[h*512+i] = -0.5f*hw*Ksq[i*8+h];
    }
}

// zb[h][i][j] = sum_c z[i,j,c] * W_b[c,h]; W_b via wave-uniform scalar loads
__global__ __launch_bounds__(128) void k_zb(const float* __restrict__ z,
        const float* __restrict__ W_b, float* __restrict__ zb) {
    __shared__ float zt[64*132];
    __shared__ float part[8*64];
    int i = blockIdx.x, j0 = blockIdx.y*64;
    int t = threadIdx.x; // 128
    #pragma unroll
    for (int l = 0; l < 16; l++) {
        int f = t + l*128;                 // 64 rows x 32 f4
        int row = f >> 5, c4 = (f & 31) << 2;
        float4 v = *(const float4*)(z + ((size_t)(i*NN) + j0 + row)*CZD + c4);
        *(float4*)(zt + row*132 + c4) = v;
    }
    __syncthreads();
    int w = t >> 6, j = t & 63;            // wave splits c-range (wave-uniform)
    int cbase = w*64;
    float acc[8] = {};
    #pragma unroll
    for (int c16 = 0; c16 < 16; c16++) {
        float4 v = *(const float4*)(zt + j*132 + cbase + c16*4);
        int c = cbase + c16*4;
        #pragma unroll
        for (int h = 0; h < 8; h++)
            acc[h] += v.x*W_b[(c+0)*8+h] + v.y*W_b[(c+1)*8+h]
                    + v.z*W_b[(c+2)*8+h] + v.w*W_b[(c+3)*8+h];
    }
    if (w == 1) {
        #pragma unroll
        for (int h = 0; h < 8; h++) part[h*64 + j] = acc[h];
    }
    __syncthreads();
    if (w == 0) {
        #pragma unroll
        for (int h = 0; h < 8; h++)
            zb[((size_t)h*512 + i)*512 + j0 + j] = acc[h] + part[h*64 + j];
    }
}

// raw scores via K=160 GEMM + affine epilogue
__global__ __launch_bounds__(256) void k_scorefill(const float* __restrict__ U, const float* __restrict__ V,
        const float* __restrict__ rowt, const float* __restrict__ colt,
        const float* __restrict__ zb, const float* __restrict__ mask,
        const float* __restrict__ sw, float* __restrict__ Am) {
    __shared__ float AsT[32*68];
    __shared__ float Bs[32*64];
    int h = blockIdx.z;
    int m0 = blockIdx.x*64, n0 = blockIdx.y*64;
    float acc[4][4] = {};
    gemm_tiles(U + (size_t)h*512*160, 160, V + (size_t)h*160*512, 512, m0, n0, 0, 5, acc, AsT, Bs);
    int tx = threadIdx.x & 15, ty = threadIdx.x >> 4;
    float swh = sw[h];
    float4 ct = *(const float4*)(colt + h*512 + n0 + tx*4);
    float4 mj = *(const float4*)(mask + n0 + tx*4);
    #pragma unroll
    for (int rr = 0; rr < 4; rr++) {
        int i = m0 + ty*4 + rr;
        float rt = rowt[h*512 + i];
        float mi = mask[i] * INFV;
        float4 zv = *(const float4*)(zb + ((size_t)h*512 + i)*512 + n0 + tx*4);
        float4 r;
        r.x = (acc[rr][0] + rt + ct.x + 0.5773502691896258f*zv.x + mi*mj.x)*swh;
        r.y = (acc[rr][1] + rt + ct.y + 0.5773502691896258f*zv.y + mi*mj.y)*swh;
        r.z = (acc[rr][2] + rt + ct.z + 0.5773502691896258f*zv.z + mi*mj.z)*swh;
        r.w = (acc[rr][3] + rt + ct.w + 0.5773502691896258f*zv.w + mi*mj.w)*swh;
        *(float4*)(Am + ((size_t)h*512 + i)*512 + n0 + tx*4) = r;
    }
}

// softmax over each (h,i) row, in-place; fuses the S-moments (o_rel reduction)
__global__ __launch_bounds__(256) void k_softmax(float* __restrict__ Am,
        const float* __restrict__ qn, const float* __restrict__ tr, float* __restrict__ S) {
    __shared__ float red[8];
    __shared__ float sred[4][8];
    int row = blockIdx.x;           // h*512 + i
    float* p = Am + (size_t)row*512;
    int t = threadIdx.x;            // 256
    float x0 = p[t], x1 = p[t+256];
    float m = fmaxf(x0, x1);
    #pragma unroll
    for (int o = 32; o > 0; o >>= 1) m = fmaxf(m, __shfl_xor(m, o));
    int wv = t >> 6, ln = t & 63;
    if (ln == 0) red[wv] = m;
    __syncthreads();
    m = fmaxf(fmaxf(red[0], red[1]), fmaxf(red[2], red[3]));
    float e0 = expf(x0 - m), e1 = expf(x1 - m);
    float sm = e0 + e1;
    #pragma unroll
    for (int o = 32; o > 0; o >>= 1) sm += __shfl_xor(sm, o);
    __syncthreads();
    if (ln == 0) red[4 + wv] = sm;
    __syncthreads();
    float inv = 1.0f / (red[4]+red[5]+red[6]+red[7]);
    float a0 = e0*inv, a1 = e1*inv;
    p[t] = a0;
    p[t+256] = a1;
    // S-moments: S[i][h*8 + {qn(4), tr(3), 1}]
    float4 q0 = *(const float4*)(qn + t*4);
    float4 q1 = *(const float4*)(qn + (t+256)*4);
    float acc[8];
    acc[0] = a0*q0.x + a1*q1.x;
    acc[1] = a0*q0.y + a1*q1.y;
    acc[2] = a0*q0.z + a1*q1.z;
    acc[3] = a0*q0.w + a1*q1.w;
    acc[4] = a0*tr[t*3+0] + a1*tr[(t+256)*3+0];
    acc[5] = a0*tr[t*3+1] + a1*tr[(t+256)*3+1];
    acc[6] = a0*tr[t*3+2] + a1*tr[(t+256)*3+2];
    acc[7] = a0 + a1;
    #pragma unroll
    for (int c = 0; c < 8; c++) {
        #pragma unroll
        for (int o = 32; o > 0; o >>= 1) acc[c] += __shfl_xor(acc[c], o);
    }
    if (ln == 0) {
        #pragma unroll
        for (int c = 0; c < 8; c++) sred[wv][c] = acc[c];
    }
    __syncthreads();
    if (t < 8) {
        int h = row >> 9, i = row & 511;
        S[i*64 + h*8 + t] = sred[0][t]+sred[1][t]+sred[2][t]+sred[3][t];
    }
}

// o and o_g in one pass: 16-row i-tile, 4 rows x 4 cols per thread
__global__ __launch_bounds__(256) void k_apply(const float* __restrict__ Am,
        const float* __restrict__ kvb, const float* __restrict__ vgg,
        float* __restrict__ obuf, float* __restrict__ og) {
    __shared__ float atT[64*20];
    int i0 = blockIdx.x*16, h = blockIdx.y;
    int t = threadIdx.x;
    int sub = t >> 6;               // wave id -> ii subrange (wave-uniform)
    int c4 = t & 63;
    bool is_o = c4 < 32;
    const float* src;
    int stride;
    if (is_o) { src = kvb + h*256 + 128 + c4*4; stride = 2048; }
    else      { src = vgg + h*128 + (c4-32)*4;  stride = 1024; }
    float acc[4][4] = {};
    for (int j0 = 0; j0 < 512; j0 += 64) {
        __syncthreads();
        #pragma unroll
        for (int l = 0; l < 4; l++) {
            int f = t + l*256;
            int ii = f >> 6, jj = f & 63;
            atT[jj*20 + ii] = Am[((size_t)h*512 + i0 + ii)*512 + j0 + jj];
        }
        __syncthreads();
        #pragma unroll 8
        for (int jj = 0; jj < 64; jj++) {
            float4 av = *(const float4*)(atT + jj*20 + sub*4);
            float4 v  = *(const float4*)(src + (size_t)(j0+jj)*stride);
            acc[0][0] += av.x*v.x; acc[0][1] += av.x*v.y; acc[0][2] += av.x*v.z; acc[0][3] += av.x*v.w;
            acc[1][0] += av.y*v.x; acc[1][1] += av.y*v.y; acc[1][2] += av.y*v.z; acc[1][3] += av.y*v.w;
            acc[2][0] += av.z*v.x; acc[2][1] += av.z*v.y; acc[2][2] += av.z*v.z; acc[2][3] += av.z*v.w;
            acc[3][0] += av.w*v.x; acc[3][1] += av.w*v.y; acc[3][2] += av.w*v.z; acc[3][3] += av.w*v.w;
        }
    }
    float* dst = is_o ? (obuf + h*128 + c4*4) : (og + h*128 + (c4-32)*4);
    #pragma unroll
    for (int q2 = 0; q2 < 4; q2++) {
        *(float4*)(dst + (size_t)(i0 + sub*4 + q2)*1024) =
            make_float4(acc[q2][0], acc[q2][1], acc[q2][2], acc[q2][3]);
    }
}

// az[i][h][zc] = sum_j a[h,i,j] * z[i,j,zc]  (second z stream)
__global__ __launch_bounds__(256) void k_az(const float* __restrict__ Am,
        const float* __restrict__ z, float* __restrict__ az) {
    __shared__ float aT[512*8];     // [j][h]
    __shared__ float part[3*1024];
    int i = blockIdx.x, t = threadIdx.x;
    #pragma unroll
    for (int l = 0; l < 16; l++) {
        int f = t + l*256;          // 0..4095
        int h = f >> 9, j = f & 511;
        aT[j*8 + h] = Am[((size_t)h*512 + i)*512 + j];
    }
    __syncthreads();
    int c2 = t & 63, quarter = t >> 6;
    int jb = quarter*128;
    float acc[8][2] = {};
    for (int j = jb; j < jb+128; j++) {
        float2 zv = *(const float2*)(z + ((size_t)(i*NN) + j)*CZD + c2*2);
        float4 a0 = *(const float4*)(aT + j*8);
        float4 a1 = *(const float4*)(aT + j*8 + 4);
        acc[0][0] += a0.x*zv.x; acc[0][1] += a0.x*zv.y;
        acc[1][0] += a0.y*zv.x; acc[1][1] += a0.y*zv.y;
        acc[2][0] += a0.z*zv.x; acc[2][1] += a0.z*zv.y;
        acc[3][0] += a0.w*zv.x; acc[3][1] += a0.w*zv.y;
        acc[4][0] += a1.x*zv.x; acc[4][1] += a1.x*zv.y;
        acc[5][0] += a1.y*zv.x; acc[5][1] += a1.y*zv.y;
        acc[6][0] += a1.z*zv.x; acc[6][1] += a1.z*zv.y;
        acc[7][0] += a1.w*zv.x; acc[7][1] += a1.w*zv.y;
    }
    if (quarter > 0) {
        #pragma unroll
        for (int h = 0; h < 8; h++) {
            part[(quarter-1)*1024 + h*128 + c2*2 + 0] = acc[h][0];
            part[(quarter-1)*1024 + h*128 + c2*2 + 1] = acc[h][1];
        }
    }
    __syncthreads();
    if (quarter == 0) {
        #pragma unroll
        for (int h = 0; h < 8; h++) {
            #pragma unroll
            for (int d = 0; d < 2; d++) {
                float sum = acc[h][d] + part[h*128 + c2*2 + d]
                          + part[1024 + h*128 + c2*2 + d] + part[2048 + h*128 + c2*2 + d];
                az[(size_t)i*1024 + h*128 + c2*2 + d] = sum;
            }
        }
    }
}

__global__ __launch_bounds__(128) void k_finalize(const float* __restrict__ obuf, const float* __restrict__ az,
                           const float* __restrict__ W_dz, const float* __restrict__ b_dz,
                           float* __restrict__ og, const float* __restrict__ S,
                           const float* __restrict__ qn, const float* __restrict__ tr,
                           float* __restrict__ feats) {
    int i=blockIdx.x, h=blockIdx.y, t=threadIdx.x; // 128
    float* f = feats + (size_t)i*2496 + h*312;
    f[32+t] = obuf[(size_t)i*1024+h*128+t];
    if (t < 32) {
        float acc = b_dz[t];
        const float* azr = az + (size_t)i*1024 + h*128;
        #pragma unroll 4
        for (int zc=0;zc<128;zc++) acc += azr[zc]*W_dz[zc*32+t];
        f[t]=acc;
    } else if (t >= 64 && t < 72) {
        int p = t-64;
        float* ogp = og + (size_t)i*1024 + h*128 + p*16;
        float in[16];
        #pragma unroll
        for (int c=0;c<16;c++) in[c]=ogp[c];
        float qc[4]={qn[i*4], -qn[i*4+1], -qn[i*4+2], -qn[i*4+3]};
        float t0=tr[i*3], t1=tr[i*3+1], t2=tr[i*3+2];
        float out[16];
        out[0]=in[0];
        qrot(qc,in+1,out+1);
        qrot(qc,in+4,out+4);
        float w=in[10];
        float tmp[3]={in[7]-w*t0, in[8]-w*t1, in[9]-w*t2};
        qrot(qc,tmp,out+7);
        #pragma unroll
        for (int c2=10;c2<16;c2++) out[c2]=in[c2];
        float n1=EPSV, n2=EPSV;
        #pragma unroll
        for (int c2=0;c2<10;c2++) n1 += out[c2]*out[c2];
        #pragma unroll
        for (int c2=10;c2<16;c2++) n2 += out[c2]*out[c2];
        n1=sqrtf(n1); n2=sqrtf(n2);
        #pragma unroll
        for (int c2=0;c2<16;c2++){ f[168+p*16+c2]=out[c2]; ogp[c2]=out[c2]; }
        f[296+p*2]=n1; f[296+p*2+1]=n2;
    } else if (t == 96) {
        float qc0=qn[i*4], qc1=-qn[i*4+1], qc2=-qn[i*4+2], qc3=-qn[i*4+3];
        const float* Sr = S + i*64 + h*8;
        float b0=Sr[0], b1=Sr[1], b2=Sr[2], b3=Sr[3];
        f[160] = qc0*b0 - qc1*b1 - qc2*b2 - qc3*b3;
        f[161] = qc0*b1 + qc1*b0 + qc2*b3 - qc3*b2;
        f[162] = qc0*b2 - qc1*b3 + qc2*b0 + qc3*b1;
        f[163] = qc0*b3 + qc1*b2 - qc2*b1 + qc3*b0;
        float A = Sr[7];
        float v[3]={Sr[4]-A*tr[i*3], Sr[5]-A*tr[i*3+1], Sr[6]-A*tr[i*3+2]};
        float qc[4]={qc0,qc1,qc2,qc3};
        float r[3]; qrot(qc,v,r);
        f[164]=r[0]; f[165]=r[1]; f[166]=r[2]; f[167]=0.0f;
    }
}

__global__ __launch_bounds__(256) void k_gout(const float* __restrict__ og, const float* __restrict__ W_geo,
                       float* __restrict__ gout) {
    int idx = blockIdx.x*blockDim.x+threadIdx.x; // 65536
    int c = idx & 15;
    int o = (idx>>4) & 7;
    int n = idx >> 7;
    float acc=0.0f;
    #pragma unroll 4
    for (int i2=0;i2<64;i2++) acc += W_geo[o*64+i2]*og[(size_t)n*1024 + i2*16 + c];
    gout[(size_t)n*128 + o*16 + c]=acc;
}

// s_out: split-K tiled GEMM with atomic accumulation (out pre-zeroed)
__global__ __launch_bounds__(256) void k_sout(const float* __restrict__ feats,
        const float* __restrict__ W_out, const float* __restrict__ b_out, float* __restrict__ out) {
    __shared__ float AsT[32*68];
    __shared__ float Bs[32*64];
    int m0 = blockIdx.x*64, n0 = blockIdx.y*64, kz = blockIdx.z;
    float acc[4][4] = {};
    gemm_tiles(feats, 2496, W_out, CSD, m0, n0, kz*416, 13, acc, AsT, Bs);
    int tx = threadIdx.x & 15, ty = threadIdx.x >> 4;
    #pragma unroll
    for (int rr = 0; rr < 4; rr++) {
        #pragma unroll
        for (int cc = 0; cc < 4; cc++) {
            float v = acc[rr][cc];
            if (kz == 0) v += b_out[n0 + tx*4 + cc];
            atomicAdd(out + (size_t)(m0+ty*4+rr)*CSD + n0 + tx*4 + cc, v);
        }
    }
}

// ---------------- launch ----------------

extern "C" void kernel_launch(void* const* d_in, const int* in_sizes, int n_in,
                              void* d_out, int out_size, void* d_ws, size_t ws_size,
                              hipStream_t stream) {
    const float* s     = (const float*)d_in[0];
    const float* g     = (const float*)d_in[1];
    const float* z     = (const float*)d_in[2];
    const float* T     = (const float*)d_in[3];
    const float* mask  = (const float*)d_in[4];
    const float* W_q   = (const float*)d_in[5];
    const float* b_q   = (const float*)d_in[6];
    const float* W_kv  = (const float*)d_in[7];
    const float* b_kv  = (const float*)d_in[8];
    const float* W_qp  = (const float*)d_in[9];
    const float* b_qp  = (const float*)d_in[10];
    const float* W_kp  = (const float*)d_in[11];
    const float* b_kp  = (const float*)d_in[12];
    const float* W_vg  = (const float*)d_in[13];
    const float* b_vg  = (const float*)d_in[14];
    const float* W_mg  = (const float*)d_in[15];
    const float* W_b   = (const float*)d_in[16];
    const float* b_b   = (const float*)d_in[17];
    const float* W_dz  = (const float*)d_in[18];
    const float* b_dz  = (const float*)d_in[19];
    const float* hw    = (const float*)d_in[20];
    const float* sw    = (const float*)d_in[21];
    const float* W_out = (const float*)d_in[22];
    const float* b_out = (const float*)d_in[23];
    const float* W_geo = (const float*)d_in[24];

    float* ws   = (float*)d_ws;
    float* out  = (float*)d_out;

    float* qn   = ws + OFF_QN;
    float* tr   = ws + OFF_TR;
    float* Qsq  = ws + OFF_QSQ;
    float* Ksq  = ws + OFF_KSQ;
    float* rowt = ws + OFF_ROWT;
    float* colt = ws + OFF_COLT;
    float* Sbuf = ws + OFF_SB;
    float* qbuf = ws + OFF_QBUF;
    float* kvb  = ws + OFF_KV;
    float* qpts = ws + OFF_QPTS;
    float* kpts = ws + OFF_KPTS;
    float* vgg  = ws + OFF_VGG;
    float* zb   = ws + OFF_ZB;
    float* Am   = ws + OFF_A;
    float* qpr  = ws + OFF_QPR;
    float* kpr  = ws + OFF_KPR;
    float* vgr  = ws + OFF_VGR;
    float* U    = ws + OFF_U;
    float* V    = ws + OFF_V;
    float* az   = ws + OFF_AZ;
    float* obuf = ws + OFF_O;
    float* og   = ws + OFF_OG;
    float* feats= ws + OFF_FEATS;

    k_prep<<<2,256,0,stream>>>(T,qn,tr);
    k_proj_all<<<dim3(8,56),256,0,stream>>>(s, W_q,b_q,qbuf, W_kv,b_kv,kvb,
                                            W_qp,b_qp,qpr, W_kp,b_kp,kpr, W_vg,b_vg,vgr);
    k_points<<<NN,64,0,stream>>>(qpr,qn,tr,qpts,Qsq);
    k_points<<<NN,64,0,stream>>>(kpr,qn,tr,kpts,Ksq);
    k_vg<<<NN,64,0,stream>>>(vgr,g,W_mg,qn,tr,vgg);
    k_uv<<<NN,256,0,stream>>>(qbuf,kvb,qpts,kpts,Qsq,Ksq,hw,b_b,U,V,rowt,colt);
    k_zb<<<dim3(NN,8),128,0,stream>>>(z,W_b,zb);
    k_scorefill<<<dim3(8,8,8),256,0,stream>>>(U,V,rowt,colt,zb,mask,sw,Am);
    k_softmax<<<4096,256,0,stream>>>(Am,qn,tr,Sbuf);
    k_apply<<<dim3(32,8),256,0,stream>>>(Am,kvb,vgg,obuf,og);
    k_az<<<NN,256,0,stream>>>(Am,z,az);
    k_finalize<<<dim3(NN,HD),128,0,stream>>>(obuf,az,W_dz,b_dz,og,Sbuf,qn,tr,feats);
    k_gout<<<256,256,0,stream>>>(og,W_geo,out + (size_t)NN*CSD);
    hipMemsetAsync(out, 0, (size_t)NN*CSD*sizeof(float), stream);
    k_sout<<<dim3(8,6,6),256,0,stream>>>(feats,W_out,b_out,out);
}

// Round 3
// 464.725 us; speedup vs baseline: 2.7330x; 1.1939x over previous
//
#include <hip/hip_runtime.h>
#include <math.h>

// ---------------- constants ----------------
#define NN 512
#define CSD 384
#define CZD 128
#define HD 8
#define CD 128
#define EPSV 1e-8f
#define INFV 100000.0f

// ---------------- ws float offsets ----------------
#define OFF_QN    ((size_t)0)
#define OFF_TR    ((size_t)2048)
#define OFF_QSQ   ((size_t)3584)
#define OFF_KSQ   ((size_t)7680)
#define OFF_ROWT  ((size_t)11776)
#define OFF_COLT  ((size_t)15872)
#define OFF_SB    ((size_t)19968)
#define OFF_QBUF  ((size_t)52736)
#define OFF_KV    ((size_t)577024)
#define OFF_QPTS  ((size_t)1625600)
#define OFF_KPTS  ((size_t)1723904)
#define OFF_VGG   ((size_t)1822208)
#define OFF_ZB    ((size_t)2346496)   // zb 2,097,152 fl; dead after k_scorefill -> reused as Vp (1,048,576 fl)
#define OFF_A     ((size_t)4443648)
#define OFF_X     ((size_t)6540800)
// union region (lifetimes disjoint, stream-ordered):
#define OFF_QPR   (OFF_X)                    // dead after k_points
#define OFF_KPR   (OFF_X + 98304)            // dead after k_points
#define OFF_VGR   (OFF_X + 196608)           // dead after k_vg
#define OFF_U     (OFF_X)                    // written k_uv, dead after scorefill
#define OFF_V     (OFF_X + 655360)           // "
#define OFF_AZ    (OFF_X)                    // written k_az (after scorefill)
#define OFF_O     (OFF_X + 524288)
#define OFF_OG    (OFF_X + 1048576)
#define OFF_FEATS (OFF_X + 1572864)
#define OFF_VP    (OFF_ZB)

__device__ __forceinline__ void qrot(const float q[4], const float* v, float* out) {
    float qw = q[0], qx = q[1], qy = q[2], qz = q[3];
    float ux = qy*v[2] - qz*v[1];
    float uy = qz*v[0] - qx*v[2];
    float uz = qx*v[1] - qy*v[0];
    float uux = qy*uz - qz*uy;
    float uuy = qz*ux - qx*uz;
    float uuz = qx*uy - qy*ux;
    out[0] = v[0] + 2.0f*(qw*ux + uux);
    out[1] = v[1] + 2.0f*(qw*uy + uuy);
    out[2] = v[2] + 2.0f*(qw*uz + uuz);
}

// ---------- shared tiled-GEMM core: 64x64 tile, BK=32, 256 thr, 4x4/thread ----------
// software-pipelined: next K-tile's global loads issued between the two barriers
__device__ __forceinline__ void gemm_tiles(const float* __restrict__ A, int lda,
                                           const float* __restrict__ B, int ldb,
                                           int m0, int n0, int k0, int nk,
                                           float acc[4][4], float* AsT, float* Bs) {
    int t = threadIdx.x;
    int tx = t & 15, ty = t >> 4;
    int arow = t >> 3, ak4 = (t & 7) << 2;
    int brow = t >> 4, bc4 = (t & 15) << 2;
    const float* Ap0 = A + (size_t)(m0 + arow)*lda + ak4;
    const float* Ap1 = A + (size_t)(m0 + arow + 32)*lda + ak4;
    const float* Bp0 = B + (size_t)brow*ldb + n0 + bc4;
    const float* Bp1 = B + (size_t)(brow + 16)*ldb + n0 + bc4;
    float4 a0 = *(const float4*)(Ap0 + k0);
    float4 a1 = *(const float4*)(Ap1 + k0);
    float4 b0 = *(const float4*)(Bp0 + (size_t)k0*ldb);
    float4 b1 = *(const float4*)(Bp1 + (size_t)k0*ldb);
    for (int kc = 0; kc < nk; kc++) {
        AsT[(ak4+0)*68 + arow] = a0.x;
        AsT[(ak4+1)*68 + arow] = a0.y;
        AsT[(ak4+2)*68 + arow] = a0.z;
        AsT[(ak4+3)*68 + arow] = a0.w;
        AsT[(ak4+0)*68 + arow+32] = a1.x;
        AsT[(ak4+1)*68 + arow+32] = a1.y;
        AsT[(ak4+2)*68 + arow+32] = a1.z;
        AsT[(ak4+3)*68 + arow+32] = a1.w;
        *(float4*)(Bs + brow*64 + bc4) = b0;
        *(float4*)(Bs + (brow+16)*64 + bc4) = b1;
        __syncthreads();
        if (kc + 1 < nk) {
            int kb = k0 + (kc+1)*32;
            a0 = *(const float4*)(Ap0 + kb);
            a1 = *(const float4*)(Ap1 + kb);
            b0 = *(const float4*)(Bp0 + (size_t)kb*ldb);
            b1 = *(const float4*)(Bp1 + (size_t)kb*ldb);
        }
        #pragma unroll
        for (int kk = 0; kk < 32; kk++) {
            float4 av = *(const float4*)(AsT + kk*68 + ty*4);
            float4 bv = *(const float4*)(Bs + kk*64 + tx*4);
            acc[0][0] += av.x*bv.x; acc[0][1] += av.x*bv.y; acc[0][2] += av.x*bv.z; acc[0][3] += av.x*bv.w;
            acc[1][0] += av.y*bv.x; acc[1][1] += av.y*bv.y; acc[1][2] += av.y*bv.z; acc[1][3] += av.y*bv.w;
            acc[2][0] += av.z*bv.x; acc[2][1] += av.z*bv.y; acc[2][2] += av.z*bv.z; acc[2][3] += av.z*bv.w;
            acc[3][0] += av.w*bv.x; acc[3][1] += av.w*bv.y; acc[3][2] += av.w*bv.z; acc[3][3] += av.w*bv.w;
        }
        __syncthreads();
    }
}

// ---------------- kernels ----------------

__global__ void k_prep(const float* __restrict__ T, float* __restrict__ qn, float* __restrict__ tr) {
    int n = blockIdx.x*blockDim.x + threadIdx.x;
    if (n >= NN) return;
    float q0=T[n*16+0], q1=T[n*16+1], q2=T[n*16+2], q3=T[n*16+3];
    float inv = 1.0f/sqrtf(q0*q0+q1*q1+q2*q2+q3*q3 + EPSV);
    qn[n*4+0]=q0*inv; qn[n*4+1]=q1*inv; qn[n*4+2]=q2*inv; qn[n*4+3]=q3*inv;
    tr[n*3+0]=T[n*16+4]; tr[n*3+1]=T[n*16+5]; tr[n*3+2]=T[n*16+6];
}

// all five projections in one launch; blockIdx.y segments the output space
__global__ __launch_bounds__(256) void k_proj_all(const float* __restrict__ s,
    const float* __restrict__ W_q,  const float* __restrict__ b_q,  float* __restrict__ qbuf,
    const float* __restrict__ W_kv, const float* __restrict__ b_kv, float* __restrict__ kvb,
    const float* __restrict__ W_qp, const float* __restrict__ b_qp, float* __restrict__ qpr,
    const float* __restrict__ W_kp, const float* __restrict__ b_kp, float* __restrict__ kpr,
    const float* __restrict__ W_vg, const float* __restrict__ b_vg, float* __restrict__ vgr) {
    __shared__ float AsT[32*68];
    __shared__ float Bs[32*64];
    int ny = blockIdx.y;
    const float* W; const float* bias; float* C; int N; int n0;
    if (ny < 16)      { W=W_q;  bias=b_q;  C=qbuf; N=1024; n0=ny*64; }
    else if (ny < 48) { W=W_kv; bias=b_kv; C=kvb;  N=2048; n0=(ny-16)*64; }
    else if (ny < 51) { W=W_qp; bias=b_qp; C=qpr;  N=192;  n0=(ny-48)*64; }
    else if (ny < 54) { W=W_kp; bias=b_kp; C=kpr;  N=192;  n0=(ny-51)*64; }
    else              { W=W_vg; bias=b_vg; C=vgr;  N=128;  n0=(ny-54)*64; }
    int m0 = blockIdx.x*64;
    float acc[4][4] = {};
    gemm_tiles(s, CSD, W, N, m0, n0, 0, 12, acc, AsT, Bs);
    int tx = threadIdx.x & 15, ty = threadIdx.x >> 4;
    float4 bb = *(const float4*)(bias + n0 + tx*4);
    #pragma unroll
    for (int rr = 0; rr < 4; rr++) {
        float4 o = make_float4(acc[rr][0]+bb.x, acc[rr][1]+bb.y, acc[rr][2]+bb.z, acc[rr][3]+bb.w);
        *(float4*)(C + (size_t)(m0+ty*4+rr)*N + n0 + tx*4) = o;
    }
}

__global__ __launch_bounds__(64) void k_points(const float* __restrict__ raw, const float* __restrict__ qn,
                         const float* __restrict__ tr, float* __restrict__ pts,
                         float* __restrict__ sq) {
    int n = blockIdx.x; int m = threadIdx.x; // 64
    float p[3] = {raw[n*192 + m], raw[n*192 + 64 + m], raw[n*192 + 128 + m]};
    float q[4] = {qn[n*4],qn[n*4+1],qn[n*4+2],qn[n*4+3]};
    float r[3]; qrot(q,p,r);
    r[0]+=tr[n*3]; r[1]+=tr[n*3+1]; r[2]+=tr[n*3+2];
    pts[n*192+m*3+0]=r[0]; pts[n*192+m*3+1]=r[1]; pts[n*192+m*3+2]=r[2];
    float s = r[0]*r[0]+r[1]*r[1]+r[2]*r[2];
    s += __shfl_down(s,4,8);
    s += __shfl_down(s,2,8);
    s += __shfl_down(s,1,8);
    if ((m&7)==0) sq[n*8 + (m>>3)] = s;
}

__global__ __launch_bounds__(64) void k_vg(const float* __restrict__ vgr, const float* __restrict__ g,
                     const float* __restrict__ W_mg, const float* __restrict__ qn,
                     const float* __restrict__ tr, float* __restrict__ vgg) {
    int n = blockIdx.x; int o = threadIdx.x; // 64
    float in[16];
    #pragma unroll
    for (int c=0;c<16;c++){
        float acc=0.0f;
        #pragma unroll
        for (int i=0;i<8;i++)  acc += W_mg[o*16+i]*vgr[n*128+i*16+c];
        #pragma unroll
        for (int i=8;i<16;i++) acc += W_mg[o*16+i]*g[n*128+(i-8)*16+c];
        in[c]=acc;
    }
    float q[4]={qn[n*4],qn[n*4+1],qn[n*4+2],qn[n*4+3]};
    float t0=tr[n*3], t1=tr[n*3+1], t2=tr[n*3+2];
    float out[16];
    out[0]=in[0];
    qrot(q,in+1,out+1);
    qrot(q,in+4,out+4);
    float w=in[10];
    qrot(q,in+7,out+7);
    out[7]+=w*t0; out[8]+=w*t1; out[9]+=w*t2;
    #pragma unroll
    for (int c=10;c<16;c++) out[c]=in[c];
    #pragma unroll
    for (int c=0;c<16;c++) vgg[(size_t)n*1024+o*16+c]=out[c];
}

// build fused score operands: U[h][i][160], V[h][160][j] (V pre-transposed), row/col terms
__global__ __launch_bounds__(256) void k_uv(const float* __restrict__ qbuf, const float* __restrict__ kvb,
                    const float* __restrict__ qpts, const float* __restrict__ kpts,
                    const float* __restrict__ Qsq, const float* __restrict__ Ksq,
                    const float* __restrict__ hwraw, const float* __restrict__ b_b,
                    float* __restrict__ U, float* __restrict__ V,
                    float* __restrict__ rowt, float* __restrict__ colt) {
    int i = blockIdx.x; int t = threadIdx.x;
    #pragma unroll
    for (int h = 0; h < 8; h++) {
        float hw = log1pf(expf(hwraw[h])) * 0.09622504486493763f; // softplus * sqrt(1/108)
        if (t < 160) {
            float u, v;
            if (t < 128) {
                u = 0.05103103630798287f * qbuf[(size_t)i*1024 + h*128 + t]; // sqrt(1/384)
                v = kvb[(size_t)i*2048 + h*256 + t];
            } else if (t < 152) {
                int d = t - 128;
                u = hw * qpts[i*192 + h*24 + d];
                v = kpts[i*192 + h*24 + d];
            } else { u = 0.0f; v = 0.0f; }
            U[((size_t)h*512 + i)*160 + t] = u;
            V[((size_t)h*160 + t)*512 + i] = v;
        }
        if (t == 160) rowt[h*512+i] = -0.5f*hw*Qsq[i*8+h] + 0.5773502691896258f*b_b[h] - INFV;
        if (t == 161) colt[h*512+i] = -0.5f*hw*Ksq[i*8+h];
    }
}

// zb[h][i][j] = sum_c z[i,j,c] * W_b[c,h]; W_b via wave-uniform scalar loads
__global__ __launch_bounds__(128) void k_zb(const float* __restrict__ z,
        const float* __restrict__ W_b, float* __restrict__ zb) {
    __shared__ float zt[64*132];
    __shared__ float part[8*64];
    int i = blockIdx.x, j0 = blockIdx.y*64;
    int t = threadIdx.x; // 128
    #pragma unroll
    for (int l = 0; l < 16; l++) {
        int f = t + l*128;                 // 64 rows x 32 f4
        int row = f >> 5, c4 = (f & 31) << 2;
        float4 v = *(const float4*)(z + ((size_t)(i*NN) + j0 + row)*CZD + c4);
        *(float4*)(zt + row*132 + c4) = v;
    }
    __syncthreads();
    int w = t >> 6, j = t & 63;            // wave splits c-range (wave-uniform)
    int cbase = w*64;
    float acc[8] = {};
    #pragma unroll
    for (int c16 = 0; c16 < 16; c16++) {
        float4 v = *(const float4*)(zt + j*132 + cbase + c16*4);
        int c = cbase + c16*4;
        #pragma unroll
        for (int h = 0; h < 8; h++)
            acc[h] += v.x*W_b[(c+0)*8+h] + v.y*W_b[(c+1)*8+h]
                    + v.z*W_b[(c+2)*8+h] + v.w*W_b[(c+3)*8+h];
    }
    if (w == 1) {
        #pragma unroll
        for (int h = 0; h < 8; h++) part[h*64 + j] = acc[h];
    }
    __syncthreads();
    if (w == 0) {
        #pragma unroll
        for (int h = 0; h < 8; h++)
            zb[((size_t)h*512 + i)*512 + j0 + j] = acc[h] + part[h*64 + j];
    }
}

// raw scores via K=160 GEMM + affine epilogue
__global__ __launch_bounds__(256) void k_scorefill(const float* __restrict__ U, const float* __restrict__ V,
        const float* __restrict__ rowt, const float* __restrict__ colt,
        const float* __restrict__ zb, const float* __restrict__ mask,
        const float* __restrict__ sw, float* __restrict__ Am) {
    __shared__ float AsT[32*68];
    __shared__ float Bs[32*64];
    int h = blockIdx.z;
    int m0 = blockIdx.x*64, n0 = blockIdx.y*64;
    float acc[4][4] = {};
    gemm_tiles(U + (size_t)h*512*160, 160, V + (size_t)h*160*512, 512, m0, n0, 0, 5, acc, AsT, Bs);
    int tx = threadIdx.x & 15, ty = threadIdx.x >> 4;
    float swh = sw[h];
    float4 ct = *(const float4*)(colt + h*512 + n0 + tx*4);
    float4 mj = *(const float4*)(mask + n0 + tx*4);
    #pragma unroll
    for (int rr = 0; rr < 4; rr++) {
        int i = m0 + ty*4 + rr;
        float rt = rowt[h*512 + i];
        float mi = mask[i] * INFV;
        float4 zv = *(const float4*)(zb + ((size_t)h*512 + i)*512 + n0 + tx*4);
        float4 r;
        r.x = (acc[rr][0] + rt + ct.x + 0.5773502691896258f*zv.x + mi*mj.x)*swh;
        r.y = (acc[rr][1] + rt + ct.y + 0.5773502691896258f*zv.y + mi*mj.y)*swh;
        r.z = (acc[rr][2] + rt + ct.z + 0.5773502691896258f*zv.z + mi*mj.z)*swh;
        r.w = (acc[rr][3] + rt + ct.w + 0.5773502691896258f*zv.w + mi*mj.w)*swh;
        *(float4*)(Am + ((size_t)h*512 + i)*512 + n0 + tx*4) = r;
    }
}

// pack Vp[h][j][0:128]=kv-v, [128:256]=vgg  (into dead zb region)
__global__ __launch_bounds__(256) void k_pack(const float* __restrict__ kvb,
        const float* __restrict__ vgg, float* __restrict__ Vp) {
    int idx = blockIdx.x*256 + threadIdx.x;   // 262144 float4s
    int c4 = idx & 63, j = (idx >> 6) & 511, h = idx >> 15;
    int col = c4*4;
    float4 v;
    if (col < 128) v = *(const float4*)(kvb + (size_t)j*2048 + h*256 + 128 + col);
    else           v = *(const float4*)(vgg + (size_t)j*1024 + h*128 + col - 128);
    *(float4*)(Vp + ((size_t)h*512 + j)*256 + col) = v;
}

// softmax over each (h,i) row, in-place; fuses the S-moments (o_rel reduction)
__global__ __launch_bounds__(256) void k_softmax(float* __restrict__ Am,
        const float* __restrict__ qn, const float* __restrict__ tr, float* __restrict__ S) {
    __shared__ float red[8];
    __shared__ float sred[4][8];
    int row = blockIdx.x;           // h*512 + i
    float* p = Am + (size_t)row*512;
    int t = threadIdx.x;            // 256
    float x0 = p[t], x1 = p[t+256];
    float m = fmaxf(x0, x1);
    #pragma unroll
    for (int o = 32; o > 0; o >>= 1) m = fmaxf(m, __shfl_xor(m, o));
    int wv = t >> 6, ln = t & 63;
    if (ln == 0) red[wv] = m;
    __syncthreads();
    m = fmaxf(fmaxf(red[0], red[1]), fmaxf(red[2], red[3]));
    float e0 = expf(x0 - m), e1 = expf(x1 - m);
    float sm = e0 + e1;
    #pragma unroll
    for (int o = 32; o > 0; o >>= 1) sm += __shfl_xor(sm, o);
    __syncthreads();
    if (ln == 0) red[4 + wv] = sm;
    __syncthreads();
    float inv = 1.0f / (red[4]+red[5]+red[6]+red[7]);
    float a0 = e0*inv, a1 = e1*inv;
    p[t] = a0;
    p[t+256] = a1;
    float4 q0 = *(const float4*)(qn + t*4);
    float4 q1 = *(const float4*)(qn + (t+256)*4);
    float acc[8];
    acc[0] = a0*q0.x + a1*q1.x;
    acc[1] = a0*q0.y + a1*q1.y;
    acc[2] = a0*q0.z + a1*q1.z;
    acc[3] = a0*q0.w + a1*q1.w;
    acc[4] = a0*tr[t*3+0] + a1*tr[(t+256)*3+0];
    acc[5] = a0*tr[t*3+1] + a1*tr[(t+256)*3+1];
    acc[6] = a0*tr[t*3+2] + a1*tr[(t+256)*3+2];
    acc[7] = a0 + a1;
    #pragma unroll
    for (int c = 0; c < 8; c++) {
        #pragma unroll
        for (int o = 32; o > 0; o >>= 1) acc[c] += __shfl_xor(acc[c], o);
    }
    if (ln == 0) {
        #pragma unroll
        for (int c = 0; c < 8; c++) sred[wv][c] = acc[c];
    }
    __syncthreads();
    if (t < 8) {
        int h = row >> 9, i = row & 511;
        S[i*64 + h*8 + t] = sred[0][t]+sred[1][t]+sred[2][t]+sred[3][t];
    }
}

// o and o_g as GEMM: C[h][512x256] = Am[h][512x512] x Vp[h][512x256], j-split 2, atomics
__global__ __launch_bounds__(256) void k_apply(const float* __restrict__ Am,
        const float* __restrict__ Vp, float* __restrict__ obuf, float* __restrict__ og) {
    __shared__ float AsT[32*68];
    __shared__ float Bs[32*64];
    int m0 = blockIdx.x*64;             // i tile
    int n0 = blockIdx.y*64;             // col tile (0..255)
    int h = blockIdx.z & 7, js = blockIdx.z >> 3;
    float acc[4][4] = {};
    gemm_tiles(Am + (size_t)h*512*512, 512, Vp + (size_t)h*512*256, 256,
               m0, n0, js*256, 8, acc, AsT, Bs);
    int tx = threadIdx.x & 15, ty = threadIdx.x >> 4;
    float* base = (n0 < 128) ? (obuf + h*128 + n0) : (og + h*128 + n0 - 128);
    #pragma unroll
    for (int rr = 0; rr < 4; rr++) {
        #pragma unroll
        for (int cc = 0; cc < 4; cc++)
            atomicAdd(base + (size_t)(m0+ty*4+rr)*1024 + tx*4 + cc, acc[rr][cc]);
    }
}

// az[i][h][zc] = sum_j a[h,i,j] * z[i,j,zc]  (second z stream)
__global__ __launch_bounds__(256) void k_az(const float* __restrict__ Am,
        const float* __restrict__ z, float* __restrict__ az) {
    __shared__ float aT[512*8];     // [j][h]
    __shared__ float part[3*1024];
    int i = blockIdx.x, t = threadIdx.x;
    #pragma unroll
    for (int l = 0; l < 16; l++) {
        int f = t + l*256;          // 0..4095
        int h = f >> 9, j = f & 511;
        aT[j*8 + h] = Am[((size_t)h*512 + i)*512 + j];
    }
    __syncthreads();
    int c2 = t & 63, quarter = t >> 6;
    int jb = quarter*128;
    float acc[8][2] = {};
    for (int j = jb; j < jb+128; j++) {
        float2 zv = *(const float2*)(z + ((size_t)(i*NN) + j)*CZD + c2*2);
        float4 a0 = *(const float4*)(aT + j*8);
        float4 a1 = *(const float4*)(aT + j*8 + 4);
        acc[0][0] += a0.x*zv.x; acc[0][1] += a0.x*zv.y;
        acc[1][0] += a0.y*zv.x; acc[1][1] += a0.y*zv.y;
        acc[2][0] += a0.z*zv.x; acc[2][1] += a0.z*zv.y;
        acc[3][0] += a0.w*zv.x; acc[3][1] += a0.w*zv.y;
        acc[4][0] += a1.x*zv.x; acc[4][1] += a1.x*zv.y;
        acc[5][0] += a1.y*zv.x; acc[5][1] += a1.y*zv.y;
        acc[6][0] += a1.z*zv.x; acc[6][1] += a1.z*zv.y;
        acc[7][0] += a1.w*zv.x; acc[7][1] += a1.w*zv.y;
    }
    if (quarter > 0) {
        #pragma unroll
        for (int h = 0; h < 8; h++) {
            part[(quarter-1)*1024 + h*128 + c2*2 + 0] = acc[h][0];
            part[(quarter-1)*1024 + h*128 + c2*2 + 1] = acc[h][1];
        }
    }
    __syncthreads();
    if (quarter == 0) {
        #pragma unroll
        for (int h = 0; h < 8; h++) {
            #pragma unroll
            for (int d = 0; d < 2; d++) {
                float sum = acc[h][d] + part[h*128 + c2*2 + d]
                          + part[1024 + h*128 + c2*2 + d] + part[2048 + h*128 + c2*2 + d];
                az[(size_t)i*1024 + h*128 + c2*2 + d] = sum;
            }
        }
    }
}

__global__ __launch_bounds__(128) void k_finalize(const float* __restrict__ obuf, const float* __restrict__ az,
                           const float* __restrict__ W_dz, const float* __restrict__ b_dz,
                           float* __restrict__ og, const float* __restrict__ S,
                           const float* __restrict__ qn, const float* __restrict__ tr,
                           float* __restrict__ feats) {
    int i=blockIdx.x, h=blockIdx.y, t=threadIdx.x; // 128
    float* f = feats + (size_t)i*2496 + h*312;
    f[32+t] = obuf[(size_t)i*1024+h*128+t];
    if (t < 32) {
        float acc = b_dz[t];
        const float* azr = az + (size_t)i*1024 + h*128;
        #pragma unroll 4
        for (int zc=0;zc<128;zc++) acc += azr[zc]*W_dz[zc*32+t];
        f[t]=acc;
    } else if (t >= 64 && t < 72) {
        int p = t-64;
        float* ogp = og + (size_t)i*1024 + h*128 + p*16;
        float in[16];
        #pragma unroll
        for (int c=0;c<16;c++) in[c]=ogp[c];
        float qc[4]={qn[i*4], -qn[i*4+1], -qn[i*4+2], -qn[i*4+3]};
        float t0=tr[i*3], t1=tr[i*3+1], t2=tr[i*3+2];
        float out[16];
        out[0]=in[0];
        qrot(qc,in+1,out+1);
        qrot(qc,in+4,out+4);
        float w=in[10];
        float tmp[3]={in[7]-w*t0, in[8]-w*t1, in[9]-w*t2};
        qrot(qc,tmp,out+7);
        #pragma unroll
        for (int c2=10;c2<16;c2++) out[c2]=in[c2];
        float n1=EPSV, n2=EPSV;
        #pragma unroll
        for (int c2=0;c2<10;c2++) n1 += out[c2]*out[c2];
        #pragma unroll
        for (int c2=10;c2<16;c2++) n2 += out[c2]*out[c2];
        n1=sqrtf(n1); n2=sqrtf(n2);
        #pragma unroll
        for (int c2=0;c2<16;c2++){ f[168+p*16+c2]=out[c2]; ogp[c2]=out[c2]; }
        f[296+p*2]=n1; f[296+p*2+1]=n2;
    } else if (t == 96) {
        float qc0=qn[i*4], qc1=-qn[i*4+1], qc2=-qn[i*4+2], qc3=-qn[i*4+3];
        const float* Sr = S + i*64 + h*8;
        float b0=Sr[0], b1=Sr[1], b2=Sr[2], b3=Sr[3];
        f[160] = qc0*b0 - qc1*b1 - qc2*b2 - qc3*b3;
        f[161] = qc0*b1 + qc1*b0 + qc2*b3 - qc3*b2;
        f[162] = qc0*b2 - qc1*b3 + qc2*b0 + qc3*b1;
        f[163] = qc0*b3 + qc1*b2 - qc2*b1 + qc3*b0;
        float A = Sr[7];
        float v[3]={Sr[4]-A*tr[i*3], Sr[5]-A*tr[i*3+1], Sr[6]-A*tr[i*3+2]};
        float qc[4]={qc0,qc1,qc2,qc3};
        float r[3]; qrot(qc,v,r);
        f[164]=r[0]; f[165]=r[1]; f[166]=r[2]; f[167]=0.0f;
    }
}

__global__ __launch_bounds__(256) void k_gout(const float* __restrict__ og, const float* __restrict__ W_geo,
                       float* __restrict__ gout) {
    int idx = blockIdx.x*blockDim.x+threadIdx.x; // 65536
    int c = idx & 15;
    int o = (idx>>4) & 7;
    int n = idx >> 7;
    float acc=0.0f;
    #pragma unroll 4
    for (int i2=0;i2<64;i2++) acc += W_geo[o*64+i2]*og[(size_t)n*1024 + i2*16 + c];
    gout[(size_t)n*128 + o*16 + c]=acc;
}

// s_out: split-K tiled GEMM with atomic accumulation (out pre-zeroed)
__global__ __launch_bounds__(256) void k_sout(const float* __restrict__ feats,
        const float* __restrict__ W_out, const float* __restrict__ b_out, float* __restrict__ out) {
    __shared__ float AsT[32*68];
    __shared__ float Bs[32*64];
    int m0 = blockIdx.x*64, n0 = blockIdx.y*64, kz = blockIdx.z;
    float acc[4][4] = {};
    gemm_tiles(feats, 2496, W_out, CSD, m0, n0, kz*416, 13, acc, AsT, Bs);
    int tx = threadIdx.x & 15, ty = threadIdx.x >> 4;
    #pragma unroll
    for (int rr = 0; rr < 4; rr++) {
        #pragma unroll
        for (int cc = 0; cc < 4; cc++) {
            float v = acc[rr][cc];
            if (kz == 0) v += b_out[n0 + tx*4 + cc];
            atomicAdd(out + (size_t)(m0+ty*4+rr)*CSD + n0 + tx*4 + cc, v);
        }
    }
}

// ---------------- launch ----------------

extern "C" void kernel_launch(void* const* d_in, const int* in_sizes, int n_in,
                              void* d_out, int out_size, void* d_ws, size_t ws_size,
                              hipStream_t stream) {
    const float* s     = (const float*)d_in[0];
    const float* g     = (const float*)d_in[1];
    const float* z     = (const float*)d_in[2];
    const float* T     = (const float*)d_in[3];
    const float* mask  = (const float*)d_in[4];
    const float* W_q   = (const float*)d_in[5];
    const float* b_q   = (const float*)d_in[6];
    const float* W_kv  = (const float*)d_in[7];
    const float* b_kv  = (const float*)d_in[8];
    const float* W_qp  = (const float*)d_in[9];
    const float* b_qp  = (const float*)d_in[10];
    const float* W_kp  = (const float*)d_in[11];
    const float* b_kp  = (const float*)d_in[12];
    const float* W_vg  = (const float*)d_in[13];
    const float* b_vg  = (const float*)d_in[14];
    const float* W_mg  = (const float*)d_in[15];
    const float* W_b   = (const float*)d_in[16];
    const float* b_b   = (const float*)d_in[17];
    const float* W_dz  = (const float*)d_in[18];
    const float* b_dz  = (const float*)d_in[19];
    const float* hw    = (const float*)d_in[20];
    const float* sw    = (const float*)d_in[21];
    const float* W_out = (const float*)d_in[22];
    const float* b_out = (const float*)d_in[23];
    const float* W_geo = (const float*)d_in[24];

    float* ws   = (float*)d_ws;
    float* out  = (float*)d_out;

    float* qn   = ws + OFF_QN;
    float* tr   = ws + OFF_TR;
    float* Qsq  = ws + OFF_QSQ;
    float* Ksq  = ws + OFF_KSQ;
    float* rowt = ws + OFF_ROWT;
    float* colt = ws + OFF_COLT;
    float* Sbuf = ws + OFF_SB;
    float* qbuf = ws + OFF_QBUF;
    float* kvb  = ws + OFF_KV;
    float* qpts = ws + OFF_QPTS;
    float* kpts = ws + OFF_KPTS;
    float* vgg  = ws + OFF_VGG;
    float* zb   = ws + OFF_ZB;
    float* Am   = ws + OFF_A;
    float* qpr  = ws + OFF_QPR;
    float* kpr  = ws + OFF_KPR;
    float* vgr  = ws + OFF_VGR;
    float* U    = ws + OFF_U;
    float* V    = ws + OFF_V;
    float* az   = ws + OFF_AZ;
    float* obuf = ws + OFF_O;
    float* og   = ws + OFF_OG;
    float* feats= ws + OFF_FEATS;
    float* Vp   = ws + OFF_VP;

    k_prep<<<2,256,0,stream>>>(T,qn,tr);
    k_proj_all<<<dim3(8,56),256,0,stream>>>(s, W_q,b_q,qbuf, W_kv,b_kv,kvb,
                                            W_qp,b_qp,qpr, W_kp,b_kp,kpr, W_vg,b_vg,vgr);
    k_points<<<NN,64,0,stream>>>(qpr,qn,tr,qpts,Qsq);
    k_points<<<NN,64,0,stream>>>(kpr,qn,tr,kpts,Ksq);
    k_vg<<<NN,64,0,stream>>>(vgr,g,W_mg,qn,tr,vgg);
    k_uv<<<NN,256,0,stream>>>(qbuf,kvb,qpts,kpts,Qsq,Ksq,hw,b_b,U,V,rowt,colt);
    k_zb<<<dim3(NN,8),128,0,stream>>>(z,W_b,zb);
    k_scorefill<<<dim3(8,8,8),256,0,stream>>>(U,V,rowt,colt,zb,mask,sw,Am);
    // zb + U/V dead from here; Vp overlays zb, obuf/og overlay U/V
    k_pack<<<1024,256,0,stream>>>(kvb,vgg,Vp);
    hipMemsetAsync(ws + OFF_O, 0, (size_t)2*512*1024*sizeof(float), stream);
    k_softmax<<<4096,256,0,stream>>>(Am,qn,tr,Sbuf);
    k_apply<<<dim3(8,4,16),256,0,stream>>>(Am,Vp,obuf,og);
    k_az<<<NN,256,0,stream>>>(Am,z,az);
    k_finalize<<<dim3(NN,HD),128,0,stream>>>(obuf,az,W_dz,b_dz,og,Sbuf,qn,tr,feats);
    k_gout<<<256,256,0,stream>>>(og,W_geo,out + (size_t)NN*CSD);
    hipMemsetAsync(out, 0, (size_t)NN*CSD*sizeof(float), stream);
    k_sout<<<dim3(8,6,6),256,0,stream>>>(feats,W_out,b_out,out);
}